// Round 3
// baseline (154.591 us; speedup 1.0000x reference)
//
#include <hip/hip_runtime.h>

// out[b] = (x @ W^T).sum(axis=1) * (0.5 * 2.0) = sum_k x[b,k] * wsum[k],
// with wsum[k] = sum_h W[h,k].
// R2 post-mortem: total 149 us = ~120 us harness resets (poison/restore) +
// ~29 us ours.  Floor for ours = 128 MiB / 6.3 TB/s ~= 20.4 us + gaps.
// This round: fold the reduce dispatch into colsum via per-stripe
// last-arrival tail (device-scope fence + atomic counter, G16 pattern);
// non-temporal loads for the read-once W / x streams.

#define N 4096            // BATCH == INPUT_SIZE == HIDDEN_SIZE
#define N4 (N / 4)        // float4 elements per row
#define P 64              // row partitions for partial column sums
#define ROWS (N / P)      // 64 rows per partial block
#define STRIPES 4         // N4 / 256 column stripes (one arrival counter each)

typedef __attribute__((ext_vector_type(4))) float f32x4;

// d_ws layout: [0,16) 4 arrival counters | [256, 256+P*N*4) partials (1 MiB)
//              | then wsum (16 KiB)
#define WS_PARTIAL_OFF 256
#define WS_WSUM_OFF (WS_PARTIAL_OFF + (size_t)P * N * 4)

// Stage 1+2 fused: partial[p][k] = sum of 64 rows; last block per column
// stripe reduces the stripe's partials into wsum.  grid (4, 64), 256 thr.
__global__ __launch_bounds__(256) void colsum_fused_kernel(
    const float* __restrict__ W, unsigned int* __restrict__ cnt,
    float* __restrict__ partial, float* __restrict__ wsum) {
    const int stripe = blockIdx.x;
    const int col4 = stripe * 256 + threadIdx.x;   // float4 column index
    const int row0 = blockIdx.y * ROWS;
    const f32x4* __restrict__ W4 = (const f32x4*)W;

    f32x4 acc = (f32x4)(0.f);
#pragma unroll
    for (int r = 0; r < ROWS; ++r)
        acc += __builtin_nontemporal_load(&W4[(size_t)(row0 + r) * N4 + col4]);

    ((f32x4*)partial)[(size_t)blockIdx.y * N4 + col4] = acc;

    // Per-stripe last-arrival: release stores, count arrivals.
    __syncthreads();                 // drains all block stores (vmcnt(0))
    __shared__ int last;
    if (threadIdx.x == 0) {
        __threadfence();             // device-scope release (L2 writeback)
        unsigned int old = atomicAdd(&cnt[stripe], 1u);
        last = (old == P - 1);
    }
    __syncthreads();

    if (last) {
        __threadfence();             // device-scope acquire (L2 invalidate)
        const f32x4* __restrict__ p4 = (const f32x4*)partial;
        f32x4 s = (f32x4)(0.f);
#pragma unroll
        for (int p = 0; p < P; ++p)
            s += p4[(size_t)p * N4 + col4];
        ((f32x4*)wsum)[col4] = s;    // visible to next kernel at launch boundary
    }
}

// Stage 3: out[b] = dot(x[b,:], wsum).  One 256-thread block per row.
__global__ __launch_bounds__(256) void rowdot_kernel(
    const float* __restrict__ x, const float* __restrict__ wsum,
    float* __restrict__ out) {
    const int b = blockIdx.x;
    const f32x4* __restrict__ x4 = (const f32x4*)(x + (size_t)b * N);
    const f32x4* __restrict__ w4 = (const f32x4*)wsum;

    float acc = 0.f;
#pragma unroll
    for (int i = threadIdx.x; i < N4; i += 256) {
        f32x4 xv = __builtin_nontemporal_load(&x4[i]);  // read-once stream
        f32x4 wv = w4[i];                               // L1/L2-resident
        acc += xv.x * wv.x + xv.y * wv.y + xv.z * wv.z + xv.w * wv.w;
    }

    // wave64 shuffle reduction
#pragma unroll
    for (int off = 32; off > 0; off >>= 1)
        acc += __shfl_down(acc, off, 64);

    __shared__ float s[4];
    if ((threadIdx.x & 63) == 0) s[threadIdx.x >> 6] = acc;
    __syncthreads();
    if (threadIdx.x == 0)
        out[b] = (s[0] + s[1] + s[2] + s[3]) * (0.5f * 2.0f);
}

extern "C" void kernel_launch(void* const* d_in, const int* in_sizes, int n_in,
                              void* d_out, int out_size, void* d_ws, size_t ws_size,
                              hipStream_t stream) {
    const float* x = (const float*)d_in[0];       // (4096, 4096) fp32
    const float* W = (const float*)d_in[1];       // (4096, 4096) fp32
    float* out = (float*)d_out;                   // (4096, 1) fp32

    unsigned int* cnt = (unsigned int*)d_ws;
    float* partial = (float*)((char*)d_ws + WS_PARTIAL_OFF);
    float* wsum    = (float*)((char*)d_ws + WS_WSUM_OFF);

    // d_ws is re-poisoned to 0xAA each call: zero just the 4 counters.
    hipMemsetAsync(cnt, 0, STRIPES * sizeof(unsigned int), stream);

    dim3 grid1(STRIPES, P);                       // (4, 64) = 256 blocks
    colsum_fused_kernel<<<grid1, 256, 0, stream>>>(W, cnt, partial, wsum);

    rowdot_kernel<<<N, 256, 0, stream>>>(x, wsum, out);
}

// Round 5
// 151.090 us; speedup vs baseline: 1.0232x; 1.0232x over previous
//
#include <hip/hip_runtime.h>

// out[b] = (x @ W^T).sum(axis=1) * (0.5 * 2.0) = sum_k x[b,k] * wsum[k],
// with wsum[k] = sum_h W[h,k].
// R5 = R2 revert (3 plain kernels, no atomics, no coop) + 1024-block colsum
// + non-temporal streaming loads.  Session arithmetic: timed window =
// ~120 us harness resets (untouchable) + our slice (floor ~23 us).
// R3 (in-kernel last-arrival fusion) = +5.3 us; R4 (cooperative) = silent
// launch failure.  This is the known-good structure, tuned.

#define N 4096            // BATCH == INPUT_SIZE == HIDDEN_SIZE
#define N4 (N / 4)        // float4 elements per row
#define P 256             // row partitions for partial column sums
#define ROWS (N / P)      // 16 rows per partial block

typedef __attribute__((ext_vector_type(4))) float f32x4;

// Stage 1: partial[g][k] = sum over 16 rows of W[., k].  Plain stores.
// grid (4, 256) = 1024 blocks (4/CU) -> full HBM streaming BW.
__global__ __launch_bounds__(256) void colsum_partial_kernel(
    const float* __restrict__ W, float* __restrict__ partial) {
    const int col4 = blockIdx.x * 256 + threadIdx.x;
    const int row0 = blockIdx.y * ROWS;
    const f32x4* __restrict__ W4 = (const f32x4*)W;

    f32x4 acc = (f32x4)(0.f);
#pragma unroll
    for (int r = 0; r < ROWS; ++r)
        acc += __builtin_nontemporal_load(&W4[(size_t)(row0 + r) * N4 + col4]);

    ((f32x4*)partial)[(size_t)blockIdx.y * N4 + col4] = acc;
}

// Stage 2: wsum[k] = sum_g partial[g][k].  16 blocks x 256 threads,
// 4 MiB read (L2/L3-resident).
__global__ __launch_bounds__(256) void colsum_reduce_kernel(
    const float* __restrict__ partial, float* __restrict__ wsum) {
    const int col4 = blockIdx.x * 256 + threadIdx.x;
    const f32x4* __restrict__ p4 = (const f32x4*)partial;

    f32x4 acc = (f32x4)(0.f);
#pragma unroll 8
    for (int g = 0; g < P; ++g)
        acc += p4[(size_t)g * N4 + col4];
    ((f32x4*)wsum)[col4] = acc;
}

// Stage 3: out[b] = dot(x[b,:], wsum).  One 256-thread block per row.
__global__ __launch_bounds__(256) void rowdot_kernel(
    const float* __restrict__ x, const float* __restrict__ wsum,
    float* __restrict__ out) {
    const int b = blockIdx.x;
    const f32x4* __restrict__ x4 = (const f32x4*)(x + (size_t)b * N);
    const f32x4* __restrict__ w4 = (const f32x4*)wsum;

    float acc = 0.f;
#pragma unroll
    for (int i = threadIdx.x; i < N4; i += 256) {
        f32x4 xv = __builtin_nontemporal_load(&x4[i]);  // read-once stream
        f32x4 wv = w4[i];                               // L2-resident
        acc += xv.x * wv.x + xv.y * wv.y + xv.z * wv.z + xv.w * wv.w;
    }

    // wave64 shuffle reduction
#pragma unroll
    for (int off = 32; off > 0; off >>= 1)
        acc += __shfl_down(acc, off, 64);

    __shared__ float s[4];
    if ((threadIdx.x & 63) == 0) s[threadIdx.x >> 6] = acc;
    __syncthreads();
    if (threadIdx.x == 0)
        out[b] = (s[0] + s[1] + s[2] + s[3]) * (0.5f * 2.0f);
}

extern "C" void kernel_launch(void* const* d_in, const int* in_sizes, int n_in,
                              void* d_out, int out_size, void* d_ws, size_t ws_size,
                              hipStream_t stream) {
    const float* x = (const float*)d_in[0];       // (4096, 4096) fp32
    const float* W = (const float*)d_in[1];       // (4096, 4096) fp32
    float* out = (float*)d_out;                   // (4096, 1) fp32

    float* partial = (float*)d_ws;                            // P * N floats = 4 MiB
    float* wsum = (float*)((char*)d_ws + (size_t)P * N * 4);  // N floats

    dim3 grid1(N4 / 256, P);                      // (4, 256) = 1024 blocks
    colsum_partial_kernel<<<grid1, 256, 0, stream>>>(W, partial);

    colsum_reduce_kernel<<<N4 / 256, 256, 0, stream>>>(partial, wsum);

    rowdot_kernel<<<N, 256, 0, stream>>>(x, wsum, out);
}